// Round 1
// baseline (358.728 us; speedup 1.0000x reference)
//
#include <hip/hip_runtime.h>
#include <hip/hip_bf16.h>
#include <math.h>

// Problem constants
#define NW 4096      // words
#define NL 32        // chars per word
#define ND 256       // D
#define ND2 512      // 2D
#define ND4 1024     // 4D

// ---------------------------------------------------------------------------
// ws layout (floats):
//   u       [4096][512]   = 2097152
//   T       [3][128][256] = 98304      (char conv tables)
//   wT      [3][256][256] = 196608     (chr conv weights transposed)
//   WsT     [3][512][512] = 786432     (sent conv weights transposed)
//   partial [512][64]     = 32768      (per-t-block max of sent conv)
// total 3,211,264 floats = 12.85 MB
// ---------------------------------------------------------------------------

// wT[k][ci][co] = conv_chr_w[co][ci][k]
__global__ __launch_bounds__(256) void transpose_chr_w(
    const float* __restrict__ src, float* __restrict__ dst) {
  int idx = blockIdx.x * 256 + threadIdx.x;           // < 196608
  float v = src[idx];
  int co = idx / 768;
  int rem = idx - co * 768;
  int ci = rem / 3;
  int k = rem - ci * 3;
  dst[k * 65536 + ci * 256 + co] = v;
}

// WsT[k][ci][co] = conv_sent_w[co][ci][k]
__global__ __launch_bounds__(256) void transpose_sent_w(
    const float* __restrict__ src, float* __restrict__ dst) {
  int idx = blockIdx.x * 256 + threadIdx.x;           // < 786432
  float v = src[idx];
  int co = idx / 1536;
  int rem = idx - co * 1536;
  int ci = rem / 3;
  int k = rem - ci * 3;
  dst[k * 262144 + ci * 512 + co] = v;
}

// T[k][c][co] = sum_ci chr_emb[c][ci] * wT[k][ci][co]
// grid: 3*128 blocks (k = b/128, c = b%128), 256 threads (co)
__global__ __launch_bounds__(256) void table_kernel(
    const float* __restrict__ chr_emb, const float* __restrict__ wT,
    float* __restrict__ T) {
  __shared__ float s_e[256];
  int k = blockIdx.x >> 7;
  int c = blockIdx.x & 127;
  int co = threadIdx.x;
  s_e[co] = chr_emb[c * 256 + co];
  __syncthreads();
  const float* wk = wT + k * 65536;
  float acc = 0.f;
#pragma unroll 8
  for (int ci = 0; ci < 256; ++ci)
    acc = fmaf(s_e[ci], wk[ci * 256 + co], acc);
  T[(k * 128 + c) * 256 + co] = acc;
}

// Per word w: u[w][0:256] = word_emb[words[w]]
//             u[w][256:512] = max_t( b + T0[c_{t-1}] + T1[c_t] + T2[c_{t+1}] )
// grid: 4096 blocks, 256 threads (co)
__global__ __launch_bounds__(256) void char_word_kernel(
    const int* __restrict__ words, const int* __restrict__ wic,
    const float* __restrict__ word_emb, const float* __restrict__ T,
    const float* __restrict__ bias, float* __restrict__ u) {
  __shared__ int s_ch[NL];
  int w = blockIdx.x;
  int co = threadIdx.x;
  if (co < NL) s_ch[co] = wic[w * NL + co];
  __syncthreads();
  int wid = words[w];
  u[w * ND2 + co] = word_emb[wid * ND + co];
  const float* T0 = T;
  const float* T1 = T + 32768;
  const float* T2 = T + 65536;
  float m = -INFINITY;
#pragma unroll
  for (int t = 0; t < NL; ++t) {
    float s = T1[s_ch[t] * ND + co];
    if (t > 0)      s += T0[s_ch[t - 1] * ND + co];
    if (t < NL - 1) s += T2[s_ch[t + 1] * ND + co];
    m = fmaxf(m, s);
  }
  u[w * ND2 + ND + co] = m + bias[co];
}

// Sentence conv as GEMM with shifted-B view + fused max epilogue.
// r[co][t] = sum_k sum_ci WsT[k][ci][co] * u[t+k-1][ci]   (bias added later)
// Block: 64 co x 64 t tile. 256 threads, 4x4 acc each. BK=16.
// partial[co][tblock] = max over this block's 64 t's.
#define BK 16
__global__ __launch_bounds__(256) void sent_conv_kernel(
    const float* __restrict__ u,     // [4096][512]
    const float* __restrict__ WsT,   // [3][512][512]
    float* __restrict__ partial) {   // [512][64]
  __shared__ float As[BK][64];       // As[i][co_l]
  __shared__ float Bs[BK][68];       // Bs[i][t_l], +4 pad: 16B-aligned rows, no big bank conflict
  const int tid = threadIdx.x;
  const int t0 = blockIdx.x * 64;
  const int co0 = blockIdx.y * 64;
  const int tx = tid & 15;   // t group
  const int ty = tid >> 4;   // co group

  float acc[4][4];
#pragma unroll
  for (int m = 0; m < 4; ++m)
#pragma unroll
    for (int n = 0; n < 4; ++n) acc[m][n] = 0.f;

  for (int k = 0; k < 3; ++k) {
    const float* Wk = WsT + k * (512 * 512);
    for (int ci0 = 0; ci0 < 512; ci0 += BK) {
      // A tile: As[i][cl] = Wk[(ci0+i)*512 + co0+cl]  (coalesced)
#pragma unroll
      for (int r = 0; r < 4; ++r) {
        int e = tid + r * 256;
        int i = e >> 6, cl = e & 63;
        As[i][cl] = Wk[(ci0 + i) * 512 + co0 + cl];
      }
      // B tile: Bs[i][tl] = u[(t0+tl+k-1)*512 + ci0+i], 0 out of range
#pragma unroll
      for (int r = 0; r < 4; ++r) {
        int e = tid + r * 256;
        int tl = e >> 4, i = e & 15;
        int trow = t0 + tl + k - 1;
        float v = 0.f;
        if (trow >= 0 && trow < NW) v = u[trow * ND2 + ci0 + i];
        Bs[i][tl] = v;
      }
      __syncthreads();
#pragma unroll
      for (int i = 0; i < BK; ++i) {
        float4 av = *(const float4*)&As[i][ty * 4];
        float4 bv = *(const float4*)&Bs[i][tx * 4];
        acc[0][0] = fmaf(av.x, bv.x, acc[0][0]);
        acc[0][1] = fmaf(av.x, bv.y, acc[0][1]);
        acc[0][2] = fmaf(av.x, bv.z, acc[0][2]);
        acc[0][3] = fmaf(av.x, bv.w, acc[0][3]);
        acc[1][0] = fmaf(av.y, bv.x, acc[1][0]);
        acc[1][1] = fmaf(av.y, bv.y, acc[1][1]);
        acc[1][2] = fmaf(av.y, bv.z, acc[1][2]);
        acc[1][3] = fmaf(av.y, bv.w, acc[1][3]);
        acc[2][0] = fmaf(av.z, bv.x, acc[2][0]);
        acc[2][1] = fmaf(av.z, bv.y, acc[2][1]);
        acc[2][2] = fmaf(av.z, bv.z, acc[2][2]);
        acc[2][3] = fmaf(av.z, bv.w, acc[2][3]);
        acc[3][0] = fmaf(av.w, bv.x, acc[3][0]);
        acc[3][1] = fmaf(av.w, bv.y, acc[3][1]);
        acc[3][2] = fmaf(av.w, bv.z, acc[3][2]);
        acc[3][3] = fmaf(av.w, bv.w, acc[3][3]);
      }
      __syncthreads();
    }
  }
  // epilogue: per-thread max over 4 t's, then reduce across the 16 tx lanes
#pragma unroll
  for (int m = 0; m < 4; ++m) {
    float v = fmaxf(fmaxf(acc[m][0], acc[m][1]), fmaxf(acc[m][2], acc[m][3]));
#pragma unroll
    for (int off = 1; off < 16; off <<= 1)
      v = fmaxf(v, __shfl_xor(v, off, 64));
    if (tx == 0) partial[(co0 + ty * 4 + m) * 64 + blockIdx.x] = v;
  }
}

// Head: r = max over t-blocks + bias; h = tanh(b1 + W1 r); out = b2 + W2 h
// single block, 1024 threads
__global__ __launch_bounds__(1024) void head_kernel(
    const float* __restrict__ partial,  // [512][64]
    const float* __restrict__ bs,       // conv_sent_b [512]
    const float* __restrict__ w1, const float* __restrict__ b1,
    const float* __restrict__ w2, const float* __restrict__ b2,
    float* __restrict__ out) {
  __shared__ float s_r[512];
  __shared__ float s_h[1024];
  int tid = threadIdx.x;
  if (tid < 512) {
    float m = -INFINITY;
    const float* p = partial + tid * 64;
#pragma unroll 8
    for (int j = 0; j < 64; ++j) m = fmaxf(m, p[j]);
    s_r[tid] = m + bs[tid];
  }
  __syncthreads();
  {
    float acc = b1[tid];
    const float4* w1v = (const float4*)(w1 + tid * 512);
    const float4* rv = (const float4*)s_r;
#pragma unroll 4
    for (int ci4 = 0; ci4 < 128; ++ci4) {
      float4 wv = w1v[ci4];
      float4 r4 = rv[ci4];
      acc = fmaf(wv.x, r4.x, acc);
      acc = fmaf(wv.y, r4.y, acc);
      acc = fmaf(wv.z, r4.z, acc);
      acc = fmaf(wv.w, r4.w, acc);
    }
    s_h[tid] = tanhf(acc);
  }
  __syncthreads();
  if (tid < 128) {
    int o = tid >> 6;
    int lane = tid & 63;
    float acc = 0.f;
#pragma unroll
    for (int j = 0; j < 16; ++j)
      acc = fmaf(w2[o * 1024 + lane + j * 64], s_h[lane + j * 64], acc);
#pragma unroll
    for (int off = 32; off >= 1; off >>= 1) acc += __shfl_down(acc, off, 64);
    if (lane == 0) out[o] = acc + b2[o];
  }
}

extern "C" void kernel_launch(void* const* d_in, const int* in_sizes, int n_in,
                              void* d_out, int out_size, void* d_ws, size_t ws_size,
                              hipStream_t stream) {
  const int*   words       = (const int*)d_in[0];
  const int*   wic         = (const int*)d_in[1];
  const float* word_emb    = (const float*)d_in[2];
  const float* chr_emb     = (const float*)d_in[3];
  const float* conv_chr_w  = (const float*)d_in[4];
  const float* conv_chr_b  = (const float*)d_in[5];
  const float* conv_sent_w = (const float*)d_in[6];
  const float* conv_sent_b = (const float*)d_in[7];
  const float* w1          = (const float*)d_in[8];
  const float* b1          = (const float*)d_in[9];
  const float* w2          = (const float*)d_in[10];
  const float* b2          = (const float*)d_in[11];
  float* out = (float*)d_out;

  float* ws      = (float*)d_ws;
  float* u_buf   = ws;                    // 2097152
  float* T_buf   = u_buf + 2097152;       // 98304
  float* wT_buf  = T_buf + 98304;         // 196608
  float* WsT_buf = wT_buf + 196608;       // 786432
  float* part    = WsT_buf + 786432;      // 32768

  transpose_chr_w<<<768, 256, 0, stream>>>(conv_chr_w, wT_buf);
  transpose_sent_w<<<3072, 256, 0, stream>>>(conv_sent_w, WsT_buf);
  table_kernel<<<384, 256, 0, stream>>>(chr_emb, wT_buf, T_buf);
  char_word_kernel<<<4096, 256, 0, stream>>>(words, wic, word_emb, T_buf,
                                             conv_chr_b, u_buf);
  sent_conv_kernel<<<dim3(64, 8), 256, 0, stream>>>(u_buf, WsT_buf, part);
  head_kernel<<<1, 1024, 0, stream>>>(part, conv_sent_b, w1, b1, w2, b2, out);
}

// Round 2
// 182.430 us; speedup vs baseline: 1.9664x; 1.9664x over previous
//
#include <hip/hip_runtime.h>
#include <hip/hip_bf16.h>
#include <math.h>

// Problem constants
#define NW 4096      // words
#define NL 32        // chars per word
#define ND 256       // D
#define ND2 512      // 2D
#define ND4 1024     // 4D

typedef __attribute__((ext_vector_type(8))) short short8;   // 8 bf16 = 4 VGPRs
typedef __attribute__((ext_vector_type(4))) float floatx4;  // MFMA acc

// ---------------------------------------------------------------------------
// ws layout:
//   T       [3][128][256] fp32   = 98304 f
//   wT      [3][256][256] fp32   = 196608 f   (chr conv weights, [k][ci][co])
//   partial [512][64]     fp32   = 32768 f
//   r       [512]         fp32
//   h       [1024]        fp32
//   u       [4098][512]   bf16   (guard row at both ends; row 0 of data = +512)
//   Wb      [3][512][512] bf16   (sent conv weights, [k][co][ci])
// ---------------------------------------------------------------------------

// wT[k][ci][co] = conv_chr_w[co][ci][k]   (fp32, feeds table_kernel)
__global__ __launch_bounds__(256) void transpose_chr_w(
    const float* __restrict__ src, float* __restrict__ dst) {
  int idx = blockIdx.x * 256 + threadIdx.x;           // < 196608
  float v = src[idx];
  int co = idx / 768;
  int rem = idx - co * 768;
  int ci = rem / 3;
  int k = rem - ci * 3;
  dst[k * 65536 + ci * 256 + co] = v;
}

// Wb[k][co][ci] = (bf16) conv_sent_w[co][ci][k]  -- K-contiguous rows for MFMA A frags
__global__ __launch_bounds__(256) void transpose_sent_w_bf16(
    const float* __restrict__ src, __hip_bfloat16* __restrict__ dst) {
  int idx = blockIdx.x * 256 + threadIdx.x;           // < 786432
  float v = src[idx];
  int co = idx / 1536;
  int rem = idx - co * 1536;
  int ci = rem / 3;
  int k = rem - ci * 3;
  dst[k * 262144 + co * 512 + ci] = __float2bfloat16(v);
}

// Zero the two guard rows of u (t = -1 and t = 4096)
__global__ __launch_bounds__(1024) void zero_guard(__hip_bfloat16* __restrict__ u_base) {
  int tid = threadIdx.x;
  if (tid < 512) u_base[tid] = __float2bfloat16(0.f);
  else           u_base[4097 * 512 + (tid - 512)] = __float2bfloat16(0.f);
}

// T[k][c][co] = sum_ci chr_emb[c][ci] * wT[k][ci][co]
__global__ __launch_bounds__(256) void table_kernel(
    const float* __restrict__ chr_emb, const float* __restrict__ wT,
    float* __restrict__ T) {
  __shared__ float s_e[256];
  int k = blockIdx.x >> 7;
  int c = blockIdx.x & 127;
  int co = threadIdx.x;
  s_e[co] = chr_emb[c * 256 + co];
  __syncthreads();
  const float* wk = wT + k * 65536;
  float acc = 0.f;
#pragma unroll 8
  for (int ci = 0; ci < 256; ++ci)
    acc = fmaf(s_e[ci], wk[ci * 256 + co], acc);
  T[(k * 128 + c) * 256 + co] = acc;
}

// Per word w: u[w][0:256] = word_emb[words[w]]  (bf16)
//             u[w][256:512] = max_t( b + T0[c_{t-1}] + T1[c_t] + T2[c_{t+1}] )
__global__ __launch_bounds__(256) void char_word_kernel(
    const int* __restrict__ words, const int* __restrict__ wic,
    const float* __restrict__ word_emb, const float* __restrict__ T,
    const float* __restrict__ bias, __hip_bfloat16* __restrict__ u0) {
  __shared__ int s_ch[NL];
  int w = blockIdx.x;
  int co = threadIdx.x;
  if (co < NL) s_ch[co] = wic[w * NL + co];
  __syncthreads();
  int wid = words[w];
  u0[w * ND2 + co] = __float2bfloat16(word_emb[wid * ND + co]);
  const float* T0 = T;
  const float* T1 = T + 32768;
  const float* T2 = T + 65536;
  float m = -INFINITY;
#pragma unroll
  for (int t = 0; t < NL; ++t) {
    float s = T1[s_ch[t] * ND + co];
    if (t > 0)      s += T0[s_ch[t - 1] * ND + co];
    if (t < NL - 1) s += T2[s_ch[t + 1] * ND + co];
    m = fmaxf(m, s);
  }
  u0[w * ND2 + ND + co] = __float2bfloat16(m + bias[co]);
}

// Sentence conv as bf16 MFMA GEMM with shifted-B view + fused max epilogue.
// C[co][t] = sum_k sum_ci Wb[k][co][ci] * u[t+k-1][ci]
// Block: 64co x 64t. 4 waves as 2x2, each wave 32x32 via 2x2 MFMA frags. BK=64.
__global__ __launch_bounds__(256) void sent_conv_mfma(
    const __hip_bfloat16* __restrict__ u0,   // row 0; rows -1..4096 valid (guards zeroed)
    const __hip_bfloat16* __restrict__ Wb,   // [3][512 co][512 ci] bf16
    float* __restrict__ partial) {           // [512][64] (co, t-block)
  __shared__ short As[64][64];   // [co_local][k] 8 KB
  __shared__ short Bs[64][64];   // [t_local][k]  8 KB
  __shared__ float sm[4][32];    // per-wave col-max staging
  const int tid = threadIdx.x;
  const int t0 = blockIdx.x * 64;
  const int co0 = blockIdx.y * 64;
  const int wave = tid >> 6;
  const int lane = tid & 63;
  const int wy = wave >> 1, wx = wave & 1;   // wave tile: co half, t half
  const int m = lane & 15, q = lane >> 4;

  floatx4 acc[2][2];
#pragma unroll
  for (int i = 0; i < 2; ++i)
#pragma unroll
    for (int j = 0; j < 2; ++j) acc[i][j] = (floatx4){0.f, 0.f, 0.f, 0.f};

  const int srow = tid >> 3;        // staging row (0..31 per r)
  const int sch  = tid & 7;         // staging 16B chunk within row

  for (int k = 0; k < 3; ++k) {
    const short* WbK = (const short*)Wb + k * 262144 + co0 * 512;
    const short* uK  = (const short*)u0 + (t0 + k - 1) * 512;
    for (int ci0 = 0; ci0 < 512; ci0 += 64) {
#pragma unroll
      for (int r = 0; r < 2; ++r) {
        int row = srow + r * 32;
        *(uint4*)&As[row][sch * 8] = *(const uint4*)(WbK + row * 512 + ci0 + sch * 8);
        *(uint4*)&Bs[row][sch * 8] = *(const uint4*)(uK  + row * 512 + ci0 + sch * 8);
      }
      __syncthreads();
#pragma unroll
      for (int kk = 0; kk < 2; ++kk) {
        short8 a0 = *(const short8*)&As[wy * 32 + m][kk * 32 + q * 8];
        short8 a1 = *(const short8*)&As[wy * 32 + 16 + m][kk * 32 + q * 8];
        short8 b0 = *(const short8*)&Bs[wx * 32 + m][kk * 32 + q * 8];
        short8 b1 = *(const short8*)&Bs[wx * 32 + 16 + m][kk * 32 + q * 8];
        acc[0][0] = __builtin_amdgcn_mfma_f32_16x16x32_bf16(a0, b0, acc[0][0], 0, 0, 0);
        acc[0][1] = __builtin_amdgcn_mfma_f32_16x16x32_bf16(a0, b1, acc[0][1], 0, 0, 0);
        acc[1][0] = __builtin_amdgcn_mfma_f32_16x16x32_bf16(a1, b0, acc[1][0], 0, 0, 0);
        acc[1][1] = __builtin_amdgcn_mfma_f32_16x16x32_bf16(a1, b1, acc[1][1], 0, 0, 0);
      }
      __syncthreads();
    }
  }

  // Epilogue: max over t within this block.
  // acc[i][j] reg r: co = co0 + wy*32 + i*16 + q*4 + r, t = t0 + wx*32 + j*16 + (lane&15)
#pragma unroll
  for (int i = 0; i < 2; ++i)
#pragma unroll
    for (int r = 0; r < 4; ++r) {
      float x = fmaxf(acc[i][0][r], acc[i][1][r]);
#pragma unroll
      for (int off = 1; off < 16; off <<= 1)
        x = fmaxf(x, __shfl_xor(x, off, 64));
      if (m == 0) sm[wave][i * 16 + q * 4 + r] = x;
    }
  __syncthreads();
  if (tid < 64) {
    int whalf = tid >> 5;  // wy
    float v = fmaxf(sm[whalf * 2 + 0][tid & 31], sm[whalf * 2 + 1][tid & 31]);
    partial[(co0 + tid) * 64 + blockIdx.x] = v;
  }
}

// r[co] = max_j partial[co][j] + conv_sent_b[co]
__global__ __launch_bounds__(512) void reduce_r(
    const float* __restrict__ partial, const float* __restrict__ bs,
    float* __restrict__ r) {
  int tid = threadIdx.x;
  const float4* p = (const float4*)(partial + tid * 64);
  float m = -INFINITY;
#pragma unroll
  for (int j = 0; j < 16; ++j) {
    float4 v = p[j];
    m = fmaxf(m, fmaxf(fmaxf(v.x, v.y), fmaxf(v.z, v.w)));
  }
  r[tid] = m + bs[tid];
}

// h[o] = tanh(b1[o] + dot(w1[o], r))  -- one wave per output
__global__ __launch_bounds__(256) void fc1_kernel(
    const float* __restrict__ r, const float* __restrict__ w1,
    const float* __restrict__ b1, float* __restrict__ h) {
  int wave = threadIdx.x >> 6;
  int lane = threadIdx.x & 63;
  int o = blockIdx.x * 4 + wave;
  const float4* wv = (const float4*)(w1 + o * 512 + lane * 8);
  const float4* rv = (const float4*)(r + lane * 8);
  float4 w0 = wv[0], w1v = wv[1];
  float4 r0 = rv[0], r1 = rv[1];
  float acc = w0.x * r0.x + w0.y * r0.y + w0.z * r0.z + w0.w * r0.w +
              w1v.x * r1.x + w1v.y * r1.y + w1v.z * r1.z + w1v.w * r1.w;
#pragma unroll
  for (int off = 32; off >= 1; off >>= 1) acc += __shfl_down(acc, off, 64);
  if (lane == 0) h[o] = tanhf(acc + b1[o]);
}

// out[o] = b2[o] + dot(w2[o], h)
__global__ __launch_bounds__(128) void fc2_kernel(
    const float* __restrict__ h, const float* __restrict__ w2,
    const float* __restrict__ b2, float* __restrict__ out) {
  int tid = threadIdx.x;
  int o = tid >> 6;
  int lane = tid & 63;
  float acc = 0.f;
#pragma unroll
  for (int j = 0; j < 16; ++j)
    acc = fmaf(w2[o * 1024 + lane + j * 64], h[lane + j * 64], acc);
#pragma unroll
  for (int off = 32; off >= 1; off >>= 1) acc += __shfl_down(acc, off, 64);
  if (lane == 0) out[o] = acc + b2[o];
}

extern "C" void kernel_launch(void* const* d_in, const int* in_sizes, int n_in,
                              void* d_out, int out_size, void* d_ws, size_t ws_size,
                              hipStream_t stream) {
  const int*   words       = (const int*)d_in[0];
  const int*   wic         = (const int*)d_in[1];
  const float* word_emb    = (const float*)d_in[2];
  const float* chr_emb     = (const float*)d_in[3];
  const float* conv_chr_w  = (const float*)d_in[4];
  const float* conv_chr_b  = (const float*)d_in[5];
  const float* conv_sent_w = (const float*)d_in[6];
  const float* conv_sent_b = (const float*)d_in[7];
  const float* w1          = (const float*)d_in[8];
  const float* b1          = (const float*)d_in[9];
  const float* w2          = (const float*)d_in[10];
  const float* b2          = (const float*)d_in[11];
  float* out = (float*)d_out;

  float* ws     = (float*)d_ws;
  float* T_buf  = ws;                     // 98304
  float* wT_buf = T_buf + 98304;          // 196608
  float* part   = wT_buf + 196608;        // 32768
  float* r_buf  = part + 32768;           // 512
  float* h_buf  = r_buf + 512;            // 1024
  __hip_bfloat16* u_base = (__hip_bfloat16*)(h_buf + 1024);  // 4098*512 bf16
  __hip_bfloat16* u0     = u_base + 512;                     // row 0
  __hip_bfloat16* Wb     = u_base + 4098 * 512;              // 3*512*512 bf16

  transpose_chr_w<<<768, 256, 0, stream>>>(conv_chr_w, wT_buf);
  transpose_sent_w_bf16<<<3072, 256, 0, stream>>>(conv_sent_w, Wb);
  zero_guard<<<1, 1024, 0, stream>>>(u_base);
  table_kernel<<<384, 256, 0, stream>>>(chr_emb, wT_buf, T_buf);
  char_word_kernel<<<4096, 256, 0, stream>>>(words, wic, word_emb, T_buf,
                                             conv_chr_b, u0);
  sent_conv_mfma<<<dim3(64, 8), 256, 0, stream>>>(u0, Wb, part);
  reduce_r<<<1, 512, 0, stream>>>(part, conv_sent_b, r_buf);
  fc1_kernel<<<256, 256, 0, stream>>>(r_buf, w1, b1, h_buf);
  fc2_kernel<<<1, 128, 0, stream>>>(h_buf, w2, b2, out);
}